// Round 6
// baseline (445.996 us; speedup 1.0000x reference)
//
#include <hip/hip_runtime.h>

// CompressiveMemory.update() — B=65536, R=K=8, D=256, fp32.
//   k0 transpose_pack: W (o,i,k) -> Wt2[m4][o][j] (m=i*2+k), 512KB in ws.
//   k1 fused_update: grid=8192, 256 thr; each block streams G=8 samples,
//      2 per iteration (8 nt-loads in flight per wave), scalar-prefetching
//      the next pair's cnt/valid. Shift samples run the 2-tap conv inline,
//      block-cooperatively (branch is block-uniform per sample).

#define NB 65536
#define RR 8
#define KK 8
#define DD 256
#define WFLOATS (DD * DD * 2)
#define G 8                      // samples per block; grid = NB/G

typedef float f4 __attribute__((ext_vector_type(4)));

static __device__ __forceinline__ f4 ntload(const float* p) {
    return __builtin_nontemporal_load((const f4*)p);
}
static __device__ __forceinline__ void ntstore(float* p, f4 v) {
    __builtin_nontemporal_store(v, (f4*)p);
}

__global__ __launch_bounds__(256) void transpose_pack(
    const float* __restrict__ W, float* __restrict__ Wt2)
{
    int t = blockIdx.x * 256 + threadIdx.x;   // coalesced read of W
    int o = t >> 9;
    int m = t & 511;                          // m = i*2 + k
    Wt2[(size_t)(m >> 2) * (DD * 4) + o * 4 + (m & 3)] = W[t];
}

// block-cooperative 2-tap conv for one shift sample; block-uniform call site
static __device__ __forceinline__ void conv_inline(
    const float* __restrict__ cmb, const float* __restrict__ fmb,
    const float* __restrict__ Wt2, const float* __restrict__ bias,
    float* __restrict__ ocm, float* xbuf, int tid)
{
    xbuf[tid * 2]     = cmb[(KK - 1) * DD + tid];   // x[2i]   = cm_last[i]
    xbuf[tid * 2 + 1] = fmb[tid];                   // x[2i+1] = fm0[i]
    __syncthreads();
    float acc = 0.f;
    const float* wp = Wt2 + tid * 4;
    #pragma unroll 8
    for (int m4 = 0; m4 < 128; ++m4) {
        const f4 wq = *(const f4*)(wp + (size_t)m4 * (DD * 4));  // 1KB/wave, coalesced, L2-hot
        const f4 xq = *(const f4*)&xbuf[m4 * 4];                 // uniform -> broadcast
        acc += xq.x * wq.x + xq.y * wq.y + xq.z * wq.z + xq.w * wq.w;
    }
    acc += bias[tid];
    ocm[(KK - 1) * DD + tid] = acc;
    __syncthreads();   // protect xbuf reuse by the next conv
}

__global__ __launch_bounds__(256) void fused_update(
    const float* __restrict__ fm,          // (B,R,D)
    const float* __restrict__ cm,          // (B,K,D)
    const int* __restrict__ cnt_in,
    const float* __restrict__ seg,         // (B,D)
    const int* __restrict__ valid,
    const float* __restrict__ Wt2,         // (128, 256, 4)
    const float* __restrict__ bias,        // (256,)
    float* __restrict__ out_fm,
    float* __restrict__ out_cm,
    float* __restrict__ out_cnt)
{
    __shared__ float xbuf[512];

    const int tid  = threadIdx.x;
    const int w    = tid >> 6;             // 0..3
    const int lane = tid & 63;
    const int c    = lane << 2;
    const int base = blockIdx.x * G;

    const int r0 = w, r1 = w + 4;

    // scalar prefetch of first pair
    int nxt_cA = cnt_in[base + 0], nxt_cB = cnt_in[base + 1];
    int nxt_vA = valid[base + 0],  nxt_vB = valid[base + 1];

    for (int j = 0; j < G; j += 2) {
        const int bA = base + j, bB = base + j + 1;
        const int cntA = nxt_cA, cntB = nxt_cB;
        const bool vA = nxt_vA != 0, vB = nxt_vB != 0;
        if (j + 2 < G) {                    // prefetch next pair
            nxt_cA = cnt_in[bA + 2]; nxt_cB = cnt_in[bB + 2];
            nxt_vA = valid[bA + 2];  nxt_vB = valid[bB + 2];
        }

        const bool insA = vA && (cntA < RR), shfA = vA && (cntA >= RR);
        const bool insB = vB && (cntB < RR), shfB = vB && (cntB >= RR);

        const float* fmA  = fm  + (size_t)bA * (RR * DD);
        const float* cmA  = cm  + (size_t)bA * (KK * DD);
        const float* segA = seg + (size_t)bA * DD;
        const float* fmB  = fm  + (size_t)bB * (RR * DD);
        const float* cmB  = cm  + (size_t)bB * (KK * DD);
        const float* segB = seg + (size_t)bB * DD;
        float* ofmA = out_fm + (size_t)bA * (RR * DD);
        float* ocmA = out_cm + (size_t)bA * (KK * DD);
        float* ofmB = out_fm + (size_t)bB * (RR * DD);
        float* ocmB = out_cm + (size_t)bB * (KK * DD);

        // source selection (wave-uniform)
        const float* f0A = shfA ? fmA + (r0 + 1) * DD
                                : (insA && r0 == cntA) ? segA : fmA + r0 * DD;
        const float* f1A = shfA ? ((r1 < 7) ? fmA + (r1 + 1) * DD : segA)
                                : (insA && r1 == cntA) ? segA : fmA + r1 * DD;
        const bool   c1A = !(shfA && r1 == 7);
        const float* c0A = cmA + (shfA ? r0 + 1 : r0) * DD;
        const float* c1Ap = c1A ? cmA + (shfA ? r1 + 1 : r1) * DD : cmA;

        const float* f0B = shfB ? fmB + (r0 + 1) * DD
                                : (insB && r0 == cntB) ? segB : fmB + r0 * DD;
        const float* f1B = shfB ? ((r1 < 7) ? fmB + (r1 + 1) * DD : segB)
                                : (insB && r1 == cntB) ? segB : fmB + r1 * DD;
        const bool   c1B = !(shfB && r1 == 7);
        const float* c0B = cmB + (shfB ? r0 + 1 : r0) * DD;
        const float* c1Bp = c1B ? cmB + (shfB ? r1 + 1 : r1) * DD : cmB;

        // issue all 8 loads (MLP=8 per wave)
        f4 a0 = ntload(f0A + c);
        f4 a1 = ntload(f1A + c);
        f4 a2 = ntload(c0A + c);
        f4 a3 = ntload(c1Ap + c);
        f4 b0 = ntload(f0B + c);
        f4 b1 = ntload(f1B + c);
        f4 b2 = ntload(c0B + c);
        f4 b3 = ntload(c1Bp + c);

        ntstore(ofmA + r0 * DD + c, a0);
        ntstore(ofmA + r1 * DD + c, a1);
        ntstore(ocmA + r0 * DD + c, a2);
        if (c1A) ntstore(ocmA + r1 * DD + c, a3);
        ntstore(ofmB + r0 * DD + c, b0);
        ntstore(ofmB + r1 * DD + c, b1);
        ntstore(ocmB + r0 * DD + c, b2);
        if (c1B) ntstore(ocmB + r1 * DD + c, b3);

        if (tid == 0) {
            out_cnt[bA] = (float)(cntA + (insA ? 1 : 0));
            out_cnt[bB] = (float)(cntB + (insB ? 1 : 0));
        }

        if (shfA) conv_inline(cmA, fmA, Wt2, bias, ocmA, xbuf, tid);
        if (shfB) conv_inline(cmB, fmB, Wt2, bias, ocmB, xbuf, tid);
    }
}

extern "C" void kernel_launch(void* const* d_in, const int* in_sizes, int n_in,
                              void* d_out, int out_size, void* d_ws, size_t ws_size,
                              hipStream_t stream) {
    const float* fm    = (const float*)d_in[0];
    const float* cm    = (const float*)d_in[1];
    const int*   cnt   = (const int*)d_in[2];
    const float* seg   = (const float*)d_in[3];
    const int*   valid = (const int*)d_in[4];
    const float* W     = (const float*)d_in[5];
    const float* bias  = (const float*)d_in[6];

    float* out_fm  = (float*)d_out;
    float* out_cm  = out_fm + (size_t)NB * RR * DD;
    float* out_cnt = out_cm + (size_t)NB * KK * DD;

    float* Wt2 = (float*)d_ws;             // 512KB

    hipLaunchKernelGGL(transpose_pack, dim3(WFLOATS / 256), dim3(256), 0, stream, W, Wt2);
    hipLaunchKernelGGL(fused_update, dim3(NB / G), dim3(256), 0, stream,
                       fm, cm, cnt, seg, valid, Wt2, bias, out_fm, out_cm, out_cnt);
}